// Round 5
// baseline (235.555 us; speedup 1.0000x reference)
//
#include <hip/hip_runtime.h>
#include <math.h>

#define NN 100000
#define F_IN 128
#define F_OUT 40
#define FH_PAD 64       // fp16 row stride: 64 elems = 128 B, 64 B-aligned -> 2 lines/gather
#define BSHIFT 9        // 512 nodes per bucket
#define BSIZE (1 << BSHIFT)
#define NBUCK ((NN + BSIZE - 1) >> BSHIFT)   // 196
#define EPB_A 4096
#define EPB_C 16384

typedef short bf16x8 __attribute__((ext_vector_type(8)));
typedef float f32x4 __attribute__((ext_vector_type(4)));

__device__ __forceinline__ short f2bf(float f) {
    union { float f; unsigned u; } uf; uf.f = f;
    unsigned r = uf.u + 0x7FFF + ((uf.u >> 16) & 1);   // RNE
    return (short)(r >> 16);
}

// ---- phase A: bucket histogram ----
__global__ void bhist_kernel(const int* __restrict__ col, int* __restrict__ bcount, int E) {
    __shared__ int h[NBUCK];
    for (int i = threadIdx.x; i < NBUCK; i += blockDim.x) h[i] = 0;
    __syncthreads();
    int e0 = blockIdx.x * EPB_A;
    int e1 = min(e0 + EPB_A, E);
    for (int e = e0 + threadIdx.x; e < e1; e += blockDim.x)
        atomicAdd(&h[col[e] >> BSHIFT], 1);
    __syncthreads();
    for (int i = threadIdx.x; i < NBUCK; i += blockDim.x)
        if (h[i]) atomicAdd(&bcount[i], h[i]);
}

// ---- phase B: scan bucket counts -> bbase; init bcursor ----
__global__ void bscan_kernel(const int* __restrict__ bcount, int* __restrict__ bbase,
                             int* __restrict__ bcursor) {
    __shared__ int sh[256];
    int i = threadIdx.x;
    int v = (i < NBUCK) ? bcount[i] : 0;
    sh[i] = v;
    __syncthreads();
    for (int off = 1; off < 256; off <<= 1) {
        int t = (i >= off) ? sh[i - off] : 0;
        __syncthreads();
        sh[i] += t;
        __syncthreads();
    }
    if (i < NBUCK) { int b = sh[i] - v; bbase[i] = b; bcursor[i] = b; }
}

// ---- phase C: partition edges; staged packs (c_local<<17)|row (row<2^17, c_local<2^9) ----
__global__ void part_kernel(const int* __restrict__ row, const int* __restrict__ col,
                            int* __restrict__ bcursor, int* __restrict__ staged, int E) {
    __shared__ int h[NBUCK];
    __shared__ int cur[NBUCK];
    for (int i = threadIdx.x; i < NBUCK; i += blockDim.x) h[i] = 0;
    __syncthreads();
    int e0 = blockIdx.x * EPB_C;
    int e1 = min(e0 + EPB_C, E);
    for (int e = e0 + threadIdx.x; e < e1; e += blockDim.x)
        atomicAdd(&h[col[e] >> BSHIFT], 1);
    __syncthreads();
    for (int i = threadIdx.x; i < NBUCK; i += blockDim.x)
        cur[i] = h[i] ? atomicAdd(&bcursor[i], h[i]) : 0;
    __syncthreads();
    for (int e = e0 + threadIdx.x; e < e1; e += blockDim.x) {
        int c = col[e];
        int pos = atomicAdd(&cur[c >> BSHIFT], 1);
        staged[pos] = ((c & (BSIZE - 1)) << 17) | row[e];
    }
}

// ---- phase D: per-bucket fine CSR build + deg/offs/ends/dinv ----
__global__ void build_kernel(const int* __restrict__ staged, const int* __restrict__ bbase,
                             int* __restrict__ adj, int* __restrict__ offs,
                             int* __restrict__ ends, float* __restrict__ dinv, int N, int E) {
    __shared__ int hist[BSIZE];
    __shared__ int cur[BSIZE];
    int bk = blockIdx.x;
    int node0 = bk << BSHIFT;
    int nn = min(BSIZE, N - node0);
    int ebase = bbase[bk];
    int eend = (bk + 1 < NBUCK) ? bbase[bk + 1] : E;
    for (int i = threadIdx.x; i < BSIZE; i += blockDim.x) hist[i] = 0;
    __syncthreads();
    for (int e = ebase + threadIdx.x; e < eend; e += blockDim.x)
        atomicAdd(&hist[staged[e] >> 17], 1);
    __syncthreads();
    int i = threadIdx.x;
    int v = (i < BSIZE) ? hist[i] : 0;
    for (int off = 1; off < BSIZE; off <<= 1) {
        int t = (i < BSIZE && i >= off) ? hist[i - off] : 0;
        __syncthreads();
        if (i < BSIZE) hist[i] += t;
        __syncthreads();
    }
    if (i < BSIZE) {
        int excl = hist[i] - v;
        cur[i] = excl;
        if (i < nn) {
            offs[node0 + i] = ebase + excl;
            ends[node0 + i] = ebase + excl + v;
            dinv[node0 + i] = rsqrtf((float)v + 1.0f);
        }
    }
    __syncthreads();
    for (int e = ebase + threadIdx.x; e < eend; e += blockDim.x) {
        int s = staged[e];
        int pos = atomicAdd(&cur[s >> 17], 1);
        adj[ebase + pos] = s & 0x1FFFF;
    }
}

// ---- MFMA gemm: xs1[n][j] = (x[n] . W[:,j]) * dinv[n]; fp16 output ----
__global__ void __launch_bounds__(256) gemm_kernel(const float* __restrict__ x,
                                                   const float* __restrict__ w,
                                                   const float* __restrict__ dinv,
                                                   _Float16* __restrict__ xs1, int N) {
    __shared__ bf16x8 shB[3][4][64];   // 12 KB packed B fragments
    int t = threadIdx.x;
    for (int idx = t; idx < 3 * 4 * 64; idx += 256) {
        int lane = idx & 63;
        int ks = (idx >> 6) & 3;
        int jt = idx >> 8;
        int j = 16 * jt + (lane & 15);
        int k0 = 32 * ks + 8 * (lane >> 4);
        bf16x8 v;
#pragma unroll
        for (int i = 0; i < 8; ++i)
            v[i] = (j < F_OUT) ? f2bf(w[(k0 + i) * F_OUT + j]) : (short)0;
        shB[jt][ks][lane] = v;
    }
    __syncthreads();
    int wave = t >> 6, lane = t & 63;
    int node0 = blockIdx.x * 64 + wave * 16;
    if (node0 >= N) return;

    const float* xrow = x + (size_t)(node0 + (lane & 15)) * F_IN + 8 * (lane >> 4);
    f32x4 acc0 = {0.f, 0.f, 0.f, 0.f};
    f32x4 acc1 = acc0, acc2 = acc0;
#pragma unroll
    for (int ks = 0; ks < 4; ++ks) {
        float4 lo = *(const float4*)(xrow + 32 * ks);
        float4 hi = *(const float4*)(xrow + 32 * ks + 4);
        bf16x8 a;
        a[0] = f2bf(lo.x); a[1] = f2bf(lo.y); a[2] = f2bf(lo.z); a[3] = f2bf(lo.w);
        a[4] = f2bf(hi.x); a[5] = f2bf(hi.y); a[6] = f2bf(hi.z); a[7] = f2bf(hi.w);
        acc0 = __builtin_amdgcn_mfma_f32_16x16x32_bf16(a, shB[0][ks][lane], acc0, 0, 0, 0);
        acc1 = __builtin_amdgcn_mfma_f32_16x16x32_bf16(a, shB[1][ks][lane], acc1, 0, 0, 0);
        acc2 = __builtin_amdgcn_mfma_f32_16x16x32_bf16(a, shB[2][ks][lane], acc2, 0, 0, 0);
    }
    int colj = lane & 15;
    int rbase = (lane >> 4) * 4;
#pragma unroll
    for (int r = 0; r < 4; ++r) {
        int node = node0 + rbase + r;
        float d = dinv[node];
        _Float16* dst = xs1 + (size_t)node * FH_PAD;
        dst[colj]      = (_Float16)(acc0[r] * d);
        dst[16 + colj] = (_Float16)(acc1[r] * d);
        if (colj < F_OUT - 32) dst[32 + colj] = (_Float16)(acc2[r] * d);
    }
}

// ---- hop 1 gather (fp16 rows, f32 accum) ----
__global__ void hop1_kernel(const int* __restrict__ offs, const int* __restrict__ ends,
                            const int* __restrict__ adj, const float* __restrict__ dinv,
                            const _Float16* __restrict__ xs, _Float16* __restrict__ xs_next,
                            int N) {
    int n = blockIdx.x * 4 + (threadIdx.x >> 6);
    int lane = threadIdx.x & 63;
    if (n >= N || lane >= F_OUT) return;
    int b = offs[n], e = ends[n];
    float a0 = (float)xs[(size_t)n * FH_PAD + lane], a1 = 0.f, a2 = 0.f, a3 = 0.f;
    int k = b;
    for (; k + 3 < e; k += 4) {
        int r0 = adj[k], r1 = adj[k + 1], r2 = adj[k + 2], r3 = adj[k + 3];
        a0 += (float)xs[(size_t)r0 * FH_PAD + lane];
        a1 += (float)xs[(size_t)r1 * FH_PAD + lane];
        a2 += (float)xs[(size_t)r2 * FH_PAD + lane];
        a3 += (float)xs[(size_t)r3 * FH_PAD + lane];
    }
    for (; k < e; ++k) a0 += (float)xs[(size_t)adj[k] * FH_PAD + lane];
    float d = dinv[n];
    xs_next[(size_t)n * FH_PAD + lane] = (_Float16)((a0 + a1 + a2 + a3) * d * d);
}

// ---- hop 2 gather + bias + log_softmax ----
__global__ void hop2_kernel(const int* __restrict__ offs, const int* __restrict__ ends,
                            const int* __restrict__ adj, const float* __restrict__ dinv,
                            const _Float16* __restrict__ xs, const float* __restrict__ bias,
                            float* __restrict__ out, int N) {
    int n = blockIdx.x * 4 + (threadIdx.x >> 6);
    int lane = threadIdx.x & 63;
    if (n >= N) return;
    int b = offs[n], e = ends[n];
    if (lane >= F_OUT) e = b;
    float a0 = (lane < F_OUT) ? (float)xs[(size_t)n * FH_PAD + lane] : 0.f;
    float a1 = 0.f, a2 = 0.f, a3 = 0.f;
    int k = b;
    for (; k + 3 < e; k += 4) {
        int r0 = adj[k], r1 = adj[k + 1], r2 = adj[k + 2], r3 = adj[k + 3];
        a0 += (float)xs[(size_t)r0 * FH_PAD + lane];
        a1 += (float)xs[(size_t)r1 * FH_PAD + lane];
        a2 += (float)xs[(size_t)r2 * FH_PAD + lane];
        a3 += (float)xs[(size_t)r3 * FH_PAD + lane];
    }
    for (; k < e; ++k) a0 += (float)xs[(size_t)adj[k] * FH_PAD + lane];

    float logit = 0.f, v = -INFINITY;
    if (lane < F_OUT) {
        logit = (a0 + a1 + a2 + a3) * dinv[n] + bias[lane];
        v = logit;
    }
#pragma unroll
    for (int off = 32; off; off >>= 1) v = fmaxf(v, __shfl_xor(v, off));
    float ex = (lane < F_OUT) ? expf(logit - v) : 0.f;
#pragma unroll
    for (int off = 32; off; off >>= 1) ex += __shfl_xor(ex, off);
    if (lane < F_OUT) out[(size_t)n * F_OUT + lane] = logit - v - logf(ex);
}

extern "C" void kernel_launch(void* const* d_in, const int* in_sizes, int n_in,
                              void* d_out, int out_size, void* d_ws, size_t ws_size,
                              hipStream_t stream) {
    const float* x    = (const float*)d_in[0];
    const int*   eidx = (const int*)d_in[1];
    const float* w    = (const float*)d_in[2];
    const float* bias = (const float*)d_in[3];
    float* out = (float*)d_out;

    const int E = in_sizes[1] / 2;
    const int N = NN;

    char* ws = (char*)d_ws;
    int*      bcount  = (int*)ws;      ws += 256 * 4;
    int*      bbase   = (int*)ws;      ws += 256 * 4;
    int*      bcursor = (int*)ws;      ws += 256 * 4;
    int*      offs    = (int*)ws;      ws += (size_t)N * 4;
    int*      ends    = (int*)ws;      ws += (size_t)N * 4;
    float*    dinv    = (float*)ws;    ws += (size_t)N * 4;
    int*      adj     = (int*)ws;      ws += (size_t)E * 4;
    _Float16* xs1     = (_Float16*)ws; ws += (size_t)N * FH_PAD * 2;
    _Float16* xs2     = (_Float16*)ws; ws += (size_t)N * FH_PAD * 2;
    int*      staged  = (int*)ws;      // 6.4 MB, own region (no aliasing risk)

    const int* row = eidx;
    const int* col = eidx + E;

    hipMemsetAsync(bcount, 0, NBUCK * sizeof(int), stream);
    bhist_kernel<<<(E + EPB_A - 1) / EPB_A, 1024, 0, stream>>>(col, bcount, E);
    bscan_kernel<<<1, 256, 0, stream>>>(bcount, bbase, bcursor);
    part_kernel<<<(E + EPB_C - 1) / EPB_C, 1024, 0, stream>>>(row, col, bcursor, staged, E);
    build_kernel<<<NBUCK, 1024, 0, stream>>>(staged, bbase, adj, offs, ends, dinv, N, E);

    gemm_kernel<<<(N + 63) / 64, 256, 0, stream>>>(x, w, dinv, xs1, N);
    hop1_kernel<<<(N + 3) / 4, 256, 0, stream>>>(offs, ends, adj, dinv, xs1, xs2, N);
    hop2_kernel<<<(N + 3) / 4, 256, 0, stream>>>(offs, ends, adj, dinv, xs2, bias, out, N);
}

// Round 6
// 187.590 us; speedup vs baseline: 1.2557x; 1.2557x over previous
//
#include <hip/hip_runtime.h>
#include <math.h>

#define NN 100000
#define F_IN 128
#define F_OUT 40
#define FH_PAD 64       // fp16 row stride: 64 elems = 128 B -> 32 dwords
#define BSHIFT 9        // 512 nodes per bucket
#define BSIZE (1 << BSHIFT)
#define NBUCK ((NN + BSIZE - 1) >> BSHIFT)   // 196
#define EPB_A 4096
#define EPB_C 16384

typedef short bf16x8 __attribute__((ext_vector_type(8)));
typedef float f32x4 __attribute__((ext_vector_type(4)));

__device__ __forceinline__ short f2bf(float f) {
    union { float f; unsigned u; } uf; uf.f = f;
    unsigned r = uf.u + 0x7FFF + ((uf.u >> 16) & 1);   // RNE
    return (short)(r >> 16);
}

__device__ __forceinline__ float2 unpack16(unsigned v) {
    union { unsigned u; _Float16 h[2]; } c; c.u = v;
    return make_float2((float)c.h[0], (float)c.h[1]);
}

__device__ __forceinline__ unsigned pack16(float x, float y) {
    union { _Float16 h; unsigned short s; } a, b;
    a.h = (_Float16)x; b.h = (_Float16)y;
    return (unsigned)a.s | ((unsigned)b.s << 16);
}

// ---- phase A: bucket histogram ----
__global__ void bhist_kernel(const int* __restrict__ col, int* __restrict__ bcount, int E) {
    __shared__ int h[NBUCK];
    for (int i = threadIdx.x; i < NBUCK; i += blockDim.x) h[i] = 0;
    __syncthreads();
    int e0 = blockIdx.x * EPB_A;
    int e1 = min(e0 + EPB_A, E);
    for (int e = e0 + threadIdx.x; e < e1; e += blockDim.x)
        atomicAdd(&h[col[e] >> BSHIFT], 1);
    __syncthreads();
    for (int i = threadIdx.x; i < NBUCK; i += blockDim.x)
        if (h[i]) atomicAdd(&bcount[i], h[i]);
}

// ---- phase B: scan bucket counts -> bbase; init bcursor ----
__global__ void bscan_kernel(const int* __restrict__ bcount, int* __restrict__ bbase,
                             int* __restrict__ bcursor) {
    __shared__ int sh[256];
    int i = threadIdx.x;
    int v = (i < NBUCK) ? bcount[i] : 0;
    sh[i] = v;
    __syncthreads();
    for (int off = 1; off < 256; off <<= 1) {
        int t = (i >= off) ? sh[i - off] : 0;
        __syncthreads();
        sh[i] += t;
        __syncthreads();
    }
    if (i < NBUCK) { int b = sh[i] - v; bbase[i] = b; bcursor[i] = b; }
}

// ---- phase C: partition edges; staged packs (c_local<<17)|row ----
__global__ void part_kernel(const int* __restrict__ row, const int* __restrict__ col,
                            int* __restrict__ bcursor, int* __restrict__ staged, int E) {
    __shared__ int h[NBUCK];
    __shared__ int cur[NBUCK];
    for (int i = threadIdx.x; i < NBUCK; i += blockDim.x) h[i] = 0;
    __syncthreads();
    int e0 = blockIdx.x * EPB_C;
    int e1 = min(e0 + EPB_C, E);
    for (int e = e0 + threadIdx.x; e < e1; e += blockDim.x)
        atomicAdd(&h[col[e] >> BSHIFT], 1);
    __syncthreads();
    for (int i = threadIdx.x; i < NBUCK; i += blockDim.x)
        cur[i] = h[i] ? atomicAdd(&bcursor[i], h[i]) : 0;
    __syncthreads();
    for (int e = e0 + threadIdx.x; e < e1; e += blockDim.x) {
        int c = col[e];
        int pos = atomicAdd(&cur[c >> BSHIFT], 1);
        staged[pos] = ((c & (BSIZE - 1)) << 17) | row[e];
    }
}

// ---- phase D: per-bucket fine CSR build + deg/offs/ends/dinv ----
__global__ void build_kernel(const int* __restrict__ staged, const int* __restrict__ bbase,
                             int* __restrict__ adj, int* __restrict__ offs,
                             int* __restrict__ ends, float* __restrict__ dinv, int N, int E) {
    __shared__ int hist[BSIZE];
    __shared__ int cur[BSIZE];
    int bk = blockIdx.x;
    int node0 = bk << BSHIFT;
    int nn = min(BSIZE, N - node0);
    int ebase = bbase[bk];
    int eend = (bk + 1 < NBUCK) ? bbase[bk + 1] : E;
    for (int i = threadIdx.x; i < BSIZE; i += blockDim.x) hist[i] = 0;
    __syncthreads();
    for (int e = ebase + threadIdx.x; e < eend; e += blockDim.x)
        atomicAdd(&hist[staged[e] >> 17], 1);
    __syncthreads();
    int i = threadIdx.x;
    int v = (i < BSIZE) ? hist[i] : 0;
    for (int off = 1; off < BSIZE; off <<= 1) {
        int t = (i < BSIZE && i >= off) ? hist[i - off] : 0;
        __syncthreads();
        if (i < BSIZE) hist[i] += t;
        __syncthreads();
    }
    if (i < BSIZE) {
        int excl = hist[i] - v;
        cur[i] = excl;
        if (i < nn) {
            offs[node0 + i] = ebase + excl;
            ends[node0 + i] = ebase + excl + v;
            dinv[node0 + i] = rsqrtf((float)v + 1.0f);
        }
    }
    __syncthreads();
    for (int e = ebase + threadIdx.x; e < eend; e += blockDim.x) {
        int s = staged[e];
        int pos = atomicAdd(&cur[s >> 17], 1);
        adj[ebase + pos] = s & 0x1FFFF;
    }
}

// ---- MFMA gemm: xs1[n][j] = (x[n] . W[:,j]) * dinv[n]; fp16 output ----
__global__ void __launch_bounds__(256) gemm_kernel(const float* __restrict__ x,
                                                   const float* __restrict__ w,
                                                   const float* __restrict__ dinv,
                                                   _Float16* __restrict__ xs1, int N) {
    __shared__ bf16x8 shB[3][4][64];
    int t = threadIdx.x;
    for (int idx = t; idx < 3 * 4 * 64; idx += 256) {
        int lane = idx & 63;
        int ks = (idx >> 6) & 3;
        int jt = idx >> 8;
        int j = 16 * jt + (lane & 15);
        int k0 = 32 * ks + 8 * (lane >> 4);
        bf16x8 v;
#pragma unroll
        for (int i = 0; i < 8; ++i)
            v[i] = (j < F_OUT) ? f2bf(w[(k0 + i) * F_OUT + j]) : (short)0;
        shB[jt][ks][lane] = v;
    }
    __syncthreads();
    int wave = t >> 6, lane = t & 63;
    int node0 = blockIdx.x * 64 + wave * 16;
    if (node0 >= N) return;

    const float* xrow = x + (size_t)(node0 + (lane & 15)) * F_IN + 8 * (lane >> 4);
    f32x4 acc0 = {0.f, 0.f, 0.f, 0.f};
    f32x4 acc1 = acc0, acc2 = acc0;
#pragma unroll
    for (int ks = 0; ks < 4; ++ks) {
        float4 lo = *(const float4*)(xrow + 32 * ks);
        float4 hi = *(const float4*)(xrow + 32 * ks + 4);
        bf16x8 a;
        a[0] = f2bf(lo.x); a[1] = f2bf(lo.y); a[2] = f2bf(lo.z); a[3] = f2bf(lo.w);
        a[4] = f2bf(hi.x); a[5] = f2bf(hi.y); a[6] = f2bf(hi.z); a[7] = f2bf(hi.w);
        acc0 = __builtin_amdgcn_mfma_f32_16x16x32_bf16(a, shB[0][ks][lane], acc0, 0, 0, 0);
        acc1 = __builtin_amdgcn_mfma_f32_16x16x32_bf16(a, shB[1][ks][lane], acc1, 0, 0, 0);
        acc2 = __builtin_amdgcn_mfma_f32_16x16x32_bf16(a, shB[2][ks][lane], acc2, 0, 0, 0);
    }
    int colj = lane & 15;
    int rbase = (lane >> 4) * 4;
#pragma unroll
    for (int r = 0; r < 4; ++r) {
        int node = node0 + rbase + r;
        float d = dinv[node];
        _Float16* dst = xs1 + (size_t)node * FH_PAD;
        dst[colj]      = (_Float16)(acc0[r] * d);
        dst[16 + colj] = (_Float16)(acc1[r] * d);
        if (colj < F_OUT - 32) dst[32 + colj] = (_Float16)(acc2[r] * d);
    }
}

// ---- hop 1: full-lane vectorized gather. wave = 2 halves x 32 lanes;
// lane (half,c2) loads dword = cols {2c2, 2c2+1}; 2 edges per load instr ----
__global__ void hop1_kernel(const int* __restrict__ offs, const int* __restrict__ ends,
                            const int* __restrict__ adj, const float* __restrict__ dinv,
                            const _Float16* __restrict__ xs, _Float16* __restrict__ xs_next,
                            int N) {
    int n = blockIdx.x * 4 + (threadIdx.x >> 6);
    int lane = threadIdx.x & 63;
    if (n >= N) return;
    int half = lane >> 5;
    int c2 = lane & 31;
    int b = offs[n], e = ends[n];
    const unsigned* base = (const unsigned*)xs;   // row = 32 dwords

    float2 a0 = {0.f, 0.f}, a1 = a0, a2 = a0, a3 = a0;
    if (half == 0) {                              // self term once
        float2 s = unpack16(base[n * 32 + c2]);
        a0.x += s.x; a0.y += s.y;
    }
    int k = b;
    for (; k + 7 < e; k += 8) {
        int r0 = adj[k + half], r1 = adj[k + 2 + half];
        int r2 = adj[k + 4 + half], r3 = adj[k + 6 + half];
        float2 f0 = unpack16(base[r0 * 32 + c2]);
        float2 f1 = unpack16(base[r1 * 32 + c2]);
        float2 f2 = unpack16(base[r2 * 32 + c2]);
        float2 f3 = unpack16(base[r3 * 32 + c2]);
        a0.x += f0.x; a0.y += f0.y;
        a1.x += f1.x; a1.y += f1.y;
        a2.x += f2.x; a2.y += f2.y;
        a3.x += f3.x; a3.y += f3.y;
    }
    for (; k + 1 < e; k += 2) {
        float2 f = unpack16(base[adj[k + half] * 32 + c2]);
        a0.x += f.x; a0.y += f.y;
    }
    if (k < e && half == 0) {
        float2 f = unpack16(base[adj[k] * 32 + c2]);
        a0.x += f.x; a0.y += f.y;
    }
    float sx = a0.x + a1.x + a2.x + a3.x;
    float sy = a0.y + a1.y + a2.y + a3.y;
    sx += __shfl_xor(sx, 32);
    sy += __shfl_xor(sy, 32);
    if (half == 0 && c2 < F_OUT / 2) {
        float d = dinv[n];
        float dd = d * d;
        ((unsigned*)xs_next)[n * 32 + c2] = pack16(sx * dd, sy * dd);
    }
}

// ---- hop 2: vectorized gather + bias + log_softmax ----
__global__ void hop2_kernel(const int* __restrict__ offs, const int* __restrict__ ends,
                            const int* __restrict__ adj, const float* __restrict__ dinv,
                            const _Float16* __restrict__ xs, const float* __restrict__ bias,
                            float* __restrict__ out, int N) {
    int n = blockIdx.x * 4 + (threadIdx.x >> 6);
    int lane = threadIdx.x & 63;
    if (n >= N) return;
    int half = lane >> 5;
    int c2 = lane & 31;
    int b = offs[n], e = ends[n];
    const unsigned* base = (const unsigned*)xs;

    float2 a0 = {0.f, 0.f}, a1 = a0, a2 = a0, a3 = a0;
    if (half == 0) {
        float2 s = unpack16(base[n * 32 + c2]);
        a0.x += s.x; a0.y += s.y;
    }
    int k = b;
    for (; k + 7 < e; k += 8) {
        int r0 = adj[k + half], r1 = adj[k + 2 + half];
        int r2 = adj[k + 4 + half], r3 = adj[k + 6 + half];
        float2 f0 = unpack16(base[r0 * 32 + c2]);
        float2 f1 = unpack16(base[r1 * 32 + c2]);
        float2 f2 = unpack16(base[r2 * 32 + c2]);
        float2 f3 = unpack16(base[r3 * 32 + c2]);
        a0.x += f0.x; a0.y += f0.y;
        a1.x += f1.x; a1.y += f1.y;
        a2.x += f2.x; a2.y += f2.y;
        a3.x += f3.x; a3.y += f3.y;
    }
    for (; k + 1 < e; k += 2) {
        float2 f = unpack16(base[adj[k + half] * 32 + c2]);
        a0.x += f.x; a0.y += f.y;
    }
    if (k < e && half == 0) {
        float2 f = unpack16(base[adj[k] * 32 + c2]);
        a0.x += f.x; a0.y += f.y;
    }
    float sx = a0.x + a1.x + a2.x + a3.x;
    float sy = a0.y + a1.y + a2.y + a3.y;
    sx += __shfl_xor(sx, 32);         // both halves now hold full sums
    sy += __shfl_xor(sy, 32);

    float lx = 0.f, ly = 0.f, v = -INFINITY;
    if (c2 < F_OUT / 2) {
        float d = dinv[n];
        float2 bb = ((const float2*)bias)[c2];
        lx = sx * d + bb.x;
        ly = sy * d + bb.y;
        v = fmaxf(lx, ly);
    }
#pragma unroll
    for (int off = 16; off; off >>= 1) v = fmaxf(v, __shfl_xor(v, off));  // per-half (dup data)
    float ex = (c2 < F_OUT / 2) ? (expf(lx - v) + expf(ly - v)) : 0.f;
#pragma unroll
    for (int off = 16; off; off >>= 1) ex += __shfl_xor(ex, off);
    if (half == 0 && c2 < F_OUT / 2) {
        float ls = v + logf(ex);
        float2 o = make_float2(lx - ls, ly - ls);
        *(float2*)(out + (size_t)n * F_OUT + 2 * c2) = o;
    }
}

extern "C" void kernel_launch(void* const* d_in, const int* in_sizes, int n_in,
                              void* d_out, int out_size, void* d_ws, size_t ws_size,
                              hipStream_t stream) {
    const float* x    = (const float*)d_in[0];
    const int*   eidx = (const int*)d_in[1];
    const float* w    = (const float*)d_in[2];
    const float* bias = (const float*)d_in[3];
    float* out = (float*)d_out;

    const int E = in_sizes[1] / 2;
    const int N = NN;

    char* ws = (char*)d_ws;
    int*      bcount  = (int*)ws;      ws += 256 * 4;
    int*      bbase   = (int*)ws;      ws += 256 * 4;
    int*      bcursor = (int*)ws;      ws += 256 * 4;
    int*      offs    = (int*)ws;      ws += (size_t)N * 4;
    int*      ends    = (int*)ws;      ws += (size_t)N * 4;
    float*    dinv    = (float*)ws;    ws += (size_t)N * 4;
    int*      adj     = (int*)ws;      ws += (size_t)E * 4;
    _Float16* xs1     = (_Float16*)ws; ws += (size_t)N * FH_PAD * 2;
    _Float16* xs2     = (_Float16*)ws; ws += (size_t)N * FH_PAD * 2;
    int*      staged  = (int*)ws;

    const int* row = eidx;
    const int* col = eidx + E;

    hipMemsetAsync(bcount, 0, NBUCK * sizeof(int), stream);
    bhist_kernel<<<(E + EPB_A - 1) / EPB_A, 1024, 0, stream>>>(col, bcount, E);
    bscan_kernel<<<1, 256, 0, stream>>>(bcount, bbase, bcursor);
    part_kernel<<<(E + EPB_C - 1) / EPB_C, 1024, 0, stream>>>(row, col, bcursor, staged, E);
    build_kernel<<<NBUCK, 1024, 0, stream>>>(staged, bbase, adj, offs, ends, dinv, N, E);

    gemm_kernel<<<(N + 63) / 64, 256, 0, stream>>>(x, w, dinv, xs1, N);
    hop1_kernel<<<(N + 3) / 4, 256, 0, stream>>>(offs, ends, adj, dinv, xs1, xs2, N);
    hop2_kernel<<<(N + 3) / 4, 256, 0, stream>>>(offs, ends, adj, dinv, xs2, bias, out, N);
}